// Round 2
// baseline (281.080 us; speedup 1.0000x reference)
//
#include <hip/hip_runtime.h>
#include <hip/hip_cooperative_groups.h>

namespace cg = cooperative_groups;

// Problem constants: B=4, S=2048, D=1024, G=256, I=1024, H=16
#define BB 4
#define SS 2048
#define DD 1024
#define II 1024

// Algebraic collapse (verified round 1): keys identical across seq -> softmax
// uniform -> out[b,s,:] = ((mean_s x[b,s,:]) @ Wv) @ Wo, broadcast over s.
// Round 2: single cooperative kernel to kill ~90 us of inter-dispatch overhead.

constexpr int NBLK = 512;             // 2 blocks/CU -> co-residency guaranteed
constexpr int NTHR = 256;
constexpr int ROWS_PER_BLK = (BB * SS) / NBLK;  // 16 rows per block in P1/P4
constexpr int JCNT = SS / ROWS_PER_BLK;          // 128 partials per batch
constexpr int KC = 32;                // split-K chunks in each gemv
constexpr int DCH = DD / KC;          // 32 k-elements per chunk

__global__ __launch_bounds__(NTHR, 4)
void fused_attention_collapse(const float* __restrict__ x,
                              const float* __restrict__ Wv,
                              const float* __restrict__ Wo,
                              float* __restrict__ out,
                              float* __restrict__ pbuf,   // [B*JCNT][DD] partials
                              float* __restrict__ tbuf,   // [B][II]  (orow follows contiguously)
                              float* __restrict__ orow) { // [B][DD]
    cg::grid_group grid = cg::this_grid();
    const int tid = threadIdx.x;
    const int g   = blockIdx.x;

    // ---------------- P1: column-sum partials over 16 rows + zero accumulators
    {
        const int b = g / JCNT;          // g = b*JCNT + j
        const int j = g % JCNT;
        const float4* xr = (const float4*)(x + ((size_t)b * SS + (size_t)j * ROWS_PER_BLK) * DD);
        float4 acc = make_float4(0.f, 0.f, 0.f, 0.f);
        #pragma unroll
        for (int r = 0; r < ROWS_PER_BLK; ++r) {
            float4 v = xr[(size_t)r * (DD / 4) + tid];
            acc.x += v.x; acc.y += v.y; acc.z += v.z; acc.w += v.w;
        }
        ((float4*)pbuf)[(size_t)g * (DD / 4) + tid] = acc;
        // zero tbuf[4096] + orow[4096] (contiguous): 8192 floats / 512 blocks
        if (tid < 16) tbuf[g * 16 + tid] = 0.f;
    }
    grid.sync();

    // ---------------- P2: xbar = reduce(pbuf)/S staged to LDS, then t = xbar @ Wv
    __shared__ float xred[2][BB][DCH];
    __shared__ float xs[BB][DCH];
    if (g < KC * 4) {
        const int kc = g >> 2, ic = g & 3;
        const int d0 = kc * DCH;
        // two-half j-reduction with 256 threads
        const int half = tid >> 7;          // 0/1
        const int e    = tid & 127;         // (b,d) element
        const int b    = e / DCH, d = e % DCH;
        float s = 0.f;
        const int j0 = half * (JCNT / 2), j1 = j0 + (JCNT / 2);
        #pragma unroll 8
        for (int j = j0; j < j1; ++j)
            s += pbuf[(size_t)(b * JCNT + j) * DD + d0 + d];
        xred[half][b][d] = s;
        __syncthreads();
        if (tid < BB * DCH)
            xs[b][d] = (xred[0][b][d] + xred[1][b][d]) * (1.0f / (float)SS);
        __syncthreads();

        const int i = ic * NTHR + tid;
        float a0 = 0.f, a1 = 0.f, a2 = 0.f, a3 = 0.f;
        #pragma unroll
        for (int d2 = 0; d2 < DCH; ++d2) {
            float w = Wv[(size_t)(d0 + d2) * II + i];
            a0 += xs[0][d2] * w;
            a1 += xs[1][d2] * w;
            a2 += xs[2][d2] * w;
            a3 += xs[3][d2] * w;
        }
        atomicAdd(&tbuf[0 * II + i], a0);
        atomicAdd(&tbuf[1 * II + i], a1);
        atomicAdd(&tbuf[2 * II + i], a2);
        atomicAdd(&tbuf[3 * II + i], a3);
    }
    grid.sync();

    // ---------------- P3: orow = t @ Wo (same split-K shape, t is complete)
    __shared__ float ts[BB][DCH];
    if (g < KC * 4) {
        const int kc = g >> 2, ic = g & 3;
        const int k0 = kc * DCH;
        if (tid < BB * DCH) {
            const int b = tid / DCH, kk = tid % DCH;
            ts[b][kk] = tbuf[b * II + k0 + kk];
        }
        __syncthreads();
        const int dcol = ic * NTHR + tid;
        float a0 = 0.f, a1 = 0.f, a2 = 0.f, a3 = 0.f;
        #pragma unroll
        for (int kk = 0; kk < DCH; ++kk) {
            float w = Wo[(size_t)(k0 + kk) * DD + dcol];
            a0 += ts[0][kk] * w;
            a1 += ts[1][kk] * w;
            a2 += ts[2][kk] * w;
            a3 += ts[3][kk] * w;
        }
        atomicAdd(&orow[0 * DD + dcol], a0);
        atomicAdd(&orow[1 * DD + dcol], a1);
        atomicAdd(&orow[2 * DD + dcol], a2);
        atomicAdd(&orow[3 * DD + dcol], a3);
    }
    grid.sync();

    // ---------------- P4: broadcast orow over 16 rows per block
    {
        const int b  = g / (NBLK / BB);       // 128 blocks per batch
        const int sg = g % (NBLK / BB);
        const int s0 = sg * ROWS_PER_BLK;
        float4 c = ((const float4*)orow)[b * (DD / 4) + tid];
        float4* o4 = (float4*)out + ((size_t)b * SS + s0) * (DD / 4) + tid;
        #pragma unroll
        for (int r = 0; r < ROWS_PER_BLK; ++r)
            o4[(size_t)r * (DD / 4)] = c;
    }
}

extern "C" void kernel_launch(void* const* d_in, const int* in_sizes, int n_in,
                              void* d_out, int out_size, void* d_ws, size_t ws_size,
                              hipStream_t stream) {
    const float* x  = (const float*)d_in[0];  // inputs_embeds [B,S,D]
    const float* Wv = (const float*)d_in[4];  // [D,I]
    const float* Wo = (const float*)d_in[5];  // [I,D]
    float* out = (float*)d_out;

    float* pbuf = (float*)d_ws;                       // 512*1024 floats = 2 MB
    float* tbuf = pbuf + (size_t)NBLK * DD;           // 4096 floats
    float* orow = tbuf + (size_t)BB * II;             // 4096 floats (contiguous after tbuf)

    void* args[] = { (void*)&x, (void*)&Wv, (void*)&Wo, (void*)&out,
                     (void*)&pbuf, (void*)&tbuf, (void*)&orow };
    hipLaunchCooperativeKernel((void*)fused_attention_collapse,
                               dim3(NBLK), dim3(NTHR), args, 0, stream);
}

// Round 3
// 171.984 us; speedup vs baseline: 1.6343x; 1.6343x over previous
//
#include <hip/hip_runtime.h>

// Problem constants: B=4, S=2048, D=1024, G=256, I=1024, H=16
#define BB 4
#define SS 2048
#define DD 1024
#define II 1024

// Algebraic collapse (verified rounds 1-2): keys identical across seq ->
// softmax uniform -> out[b,s,:] = ((mean_s x[b,s,:]) @ Wv) @ Wo broadcast
// over s. Wq/Wk/structure_features unused.
//
// Round 3: 4 plain graph nodes, no atomics / memsets / grid.sync.
//   k1: x -> pbuf partial column sums (exclusive slots)
//   k2: pbuf -> t = xbar@Wv      (each block re-reduces pbuf from L2/L3)
//   k2: t    -> orow = t@Wo      (jp=1 path)
//   k4: broadcast orow -> out

constexpr int JP = 64;            // partials per batch
constexpr int ROWS1 = SS / JP;    // 32 rows per k1 block

// k1: pbuf[b][j][:] = sum of 32 consecutive rows of x[b]
__global__ __launch_bounds__(256)
void k1_partial(const float* __restrict__ x, float4* __restrict__ pbuf) {
    const int g = blockIdx.x;                 // 256 blocks
    const int b = g >> 6, j = g & 63;
    const float4* xr = (const float4*)x + (size_t)(b * SS + j * ROWS1) * (DD / 4) + threadIdx.x;
    float4 a = make_float4(0.f, 0.f, 0.f, 0.f);
    #pragma unroll
    for (int r = 0; r < ROWS1; ++r) {
        float4 v = xr[(size_t)r * (DD / 4)];
        a.x += v.x; a.y += v.y; a.z += v.z; a.w += v.w;
    }
    pbuf[(size_t)g * (DD / 4) + threadIdx.x] = a;
}

// k2: vout[b][i0:i0+16] = (scale * reduce_j vin[b][j][:]) @ W
// vin: [BB][jp][1024] (jp=1 => plain vector). W: [1024][1024] row-major.
// 64 blocks x 256 threads; block owns a 16-wide output slice (non-atomic).
__global__ __launch_bounds__(256)
void k2_gemv(const float* __restrict__ vin, const float* __restrict__ W,
             float* __restrict__ vout, int jp, float scale) {
    __shared__ float xs[BB][DD];          // 16 KB
    const int tid = threadIdx.x;
    for (int b = 0; b < BB; ++b) {
        const float4* p = (const float4*)(vin + (size_t)b * jp * DD) + tid;
        float4 a = make_float4(0.f, 0.f, 0.f, 0.f);
        for (int j = 0; j < jp; ++j) {
            float4 v = p[(size_t)j * (DD / 4)];
            a.x += v.x; a.y += v.y; a.z += v.z; a.w += v.w;
        }
        ((float4*)xs[b])[tid] = make_float4(a.x * scale, a.y * scale, a.z * scale, a.w * scale);
    }
    __syncthreads();

    const int i0 = blockIdx.x * 16;
    const int il = tid & 15, ks = tid >> 4;     // 16-way k-split, 64 k each
    float acc[BB] = {0.f, 0.f, 0.f, 0.f};
    #pragma unroll 8
    for (int kk = 0; kk < 64; ++kk) {
        const int k = ks * 64 + kk;
        const float w = W[(size_t)k * 1024 + i0 + il];
        #pragma unroll
        for (int b = 0; b < BB; ++b) acc[b] += xs[b][k] * w;
    }

    __shared__ float red[16][BB][16];
    #pragma unroll
    for (int b = 0; b < BB; ++b) red[ks][b][il] = acc[b];
    __syncthreads();
    if (tid < BB * 16) {
        const int b = tid >> 4, i = tid & 15;
        float s = 0.f;
        #pragma unroll
        for (int q = 0; q < 16; ++q) s += red[q][b][i];
        vout[b * 1024 + i0 + i] = s;
    }
}

// k4: out[b][s][:] = orow[b][:], 4 rows per block, float4 stores
__global__ __launch_bounds__(256)
void k4_bcast(const float* __restrict__ orow, float4* __restrict__ out) {
    const int g = blockIdx.x;                 // 2048 blocks
    const int b = g >> 9;
    const int s0 = (g & 511) * 4;
    const float4 c = ((const float4*)(orow + b * DD))[threadIdx.x];
    float4* o = out + (size_t)(b * SS + s0) * (DD / 4) + threadIdx.x;
    #pragma unroll
    for (int r = 0; r < 4; ++r) o[(size_t)r * (DD / 4)] = c;
}

extern "C" void kernel_launch(void* const* d_in, const int* in_sizes, int n_in,
                              void* d_out, int out_size, void* d_ws, size_t ws_size,
                              hipStream_t stream) {
    const float* x  = (const float*)d_in[0];  // inputs_embeds [B,S,D]
    const float* Wv = (const float*)d_in[4];  // [D,I]
    const float* Wo = (const float*)d_in[5];  // [I,D]
    float* out = (float*)d_out;

    float* pbuf = (float*)d_ws;                       // BB*JP*DD = 262144 floats (1 MB)
    float* tvec = pbuf + (size_t)BB * JP * DD;        // [BB][II]
    float* orow = tvec + (size_t)BB * II;             // [BB][DD]

    k1_partial<<<BB * JP, 256, 0, stream>>>(x, (float4*)pbuf);
    k2_gemv<<<II / 16, 256, 0, stream>>>(pbuf, Wv, tvec, JP, 1.0f / (float)SS);
    k2_gemv<<<DD / 16, 256, 0, stream>>>(tvec, Wo, orow, 1, 1.0f);
    k4_bcast<<<(BB * SS) / 4, 256, 0, stream>>>(orow, (float4*)out);
}

// Round 4
// 116.504 us; speedup vs baseline: 2.4126x; 1.4762x over previous
//
#include <hip/hip_runtime.h>

// Problem constants: B=4, S=2048, D=1024, G=256, I=1024, H=16
#define BB 4
#define SS 2048
#define DD 1024
#define II 1024

// Algebraic collapse (verified rounds 1-3): keys identical across seq ->
// softmax uniform -> out[b,s,:] = ((mean_s x[b,s,:]) @ Wv) @ Wo broadcast
// over s. Wq/Wk/structure_features unused.
//
// Round 4: all loops compile-time (full unroll -> deep MLP); dedicated
// reduction kernel so the pbuf reduction happens once, not per-gemv-block.
//   k1   (512 blk): x -> pbuf[4][128][1024] partial column sums
//   kred (  4 blk): pbuf -> xbar[4][1024] (scaled by 1/S)
//   kg   ( 64 blk): t = xbar@Wv ; then orow = t@Wo (two launches)
//   k4   (2048 blk): broadcast orow -> out

constexpr int JP = 128;            // partials per batch
constexpr int ROWS1 = SS / JP;     // 16 rows per k1 block

// k1: pbuf[g][:] = sum of 16 consecutive rows of x  (g = b*128 + j)
__global__ __launch_bounds__(256)
void k1_partial(const float4* __restrict__ x, float4* __restrict__ pbuf) {
    const int g = blockIdx.x;                 // 512 blocks
    const float4* xr = x + (size_t)g * ROWS1 * (DD / 4) + threadIdx.x;
    float4 a = make_float4(0.f, 0.f, 0.f, 0.f);
    #pragma unroll
    for (int r = 0; r < ROWS1; ++r) {
        float4 v = xr[(size_t)r * (DD / 4)];
        a.x += v.x; a.y += v.y; a.z += v.z; a.w += v.w;
    }
    pbuf[(size_t)g * (DD / 4) + threadIdx.x] = a;
}

// kred: xbar[b][:] = (1/S) * sum_j pbuf[b][j][:]   (4 blocks, full unroll)
__global__ __launch_bounds__(256)
void kred(const float4* __restrict__ pbuf, float4* __restrict__ xbar) {
    const int b = blockIdx.x;
    const float4* p = pbuf + (size_t)b * JP * (DD / 4) + threadIdx.x;
    float4 a = make_float4(0.f, 0.f, 0.f, 0.f);
    #pragma unroll
    for (int j = 0; j < JP; ++j) {
        float4 v = p[(size_t)j * (DD / 4)];
        a.x += v.x; a.y += v.y; a.z += v.z; a.w += v.w;
    }
    const float s = 1.0f / (float)SS;
    xbar[(size_t)b * (DD / 4) + threadIdx.x] =
        make_float4(a.x * s, a.y * s, a.z * s, a.w * s);
}

// kg: out[b][i0:i0+16] = vec[b][:] @ W   (vec: [4][1024], W: [1024][1024])
// 64 blocks x 256 threads; block owns a 16-wide output slice; 16-way k-split.
__global__ __launch_bounds__(256)
void kg_gemv(const float4* __restrict__ vec, const float* __restrict__ W,
             float* __restrict__ out) {
    __shared__ float xs[BB * DD];             // 16 KB
    const int tid = threadIdx.x;
    #pragma unroll
    for (int q = 0; q < 4; ++q)
        ((float4*)xs)[q * 256 + tid] = vec[q * 256 + tid];
    __syncthreads();

    const int i0 = blockIdx.x * 16;
    const int il = tid & 15, ks = tid >> 4;   // 16 k-groups of 64
    float acc[BB] = {0.f, 0.f, 0.f, 0.f};
    #pragma unroll
    for (int kk = 0; kk < 64; ++kk) {
        const int k = ks * 64 + kk;
        const float w = W[(size_t)k * DD + i0 + il];
        #pragma unroll
        for (int b = 0; b < BB; ++b) acc[b] += xs[b * DD + k] * w;
    }

    __shared__ float red[16][BB][16];         // 4 KB
    #pragma unroll
    for (int b = 0; b < BB; ++b) red[ks][b][il] = acc[b];
    __syncthreads();
    if (tid < BB * 16) {
        const int b = tid >> 4, i = tid & 15;
        float s = 0.f;
        #pragma unroll
        for (int q = 0; q < 16; ++q) s += red[q][b][i];
        out[b * DD + i0 + i] = s;
    }
}

// k4: out[b][s][:] = orow[b][:], 4 rows per block, float4 stores
__global__ __launch_bounds__(256)
void k4_bcast(const float4* __restrict__ orow, float4* __restrict__ out) {
    const int g = blockIdx.x;                 // 2048 blocks
    const int b = g >> 9;
    const int s0 = (g & 511) * 4;
    const float4 c = orow[b * (DD / 4) + threadIdx.x];
    float4* o = out + (size_t)(b * SS + s0) * (DD / 4) + threadIdx.x;
    #pragma unroll
    for (int r = 0; r < 4; ++r) o[(size_t)r * (DD / 4)] = c;
}

extern "C" void kernel_launch(void* const* d_in, const int* in_sizes, int n_in,
                              void* d_out, int out_size, void* d_ws, size_t ws_size,
                              hipStream_t stream) {
    const float* x  = (const float*)d_in[0];  // inputs_embeds [B,S,D]
    const float* Wv = (const float*)d_in[4];  // [D,I]
    const float* Wo = (const float*)d_in[5];  // [I,D]
    float* out = (float*)d_out;

    float* pbuf = (float*)d_ws;                       // BB*JP*DD = 524288 floats (2 MB)
    float* xbar = pbuf + (size_t)BB * JP * DD;        // [4][1024]
    float* tvec = xbar + (size_t)BB * DD;             // [4][1024]
    float* orow = tvec + (size_t)BB * II;             // [4][1024]

    k1_partial<<<BB * JP, 256, 0, stream>>>((const float4*)x, (float4*)pbuf);
    kred<<<BB, 256, 0, stream>>>((const float4*)pbuf, (float4*)xbar);
    kg_gemv<<<II / 16, 256, 0, stream>>>((const float4*)xbar, Wv, tvec);
    kg_gemv<<<DD / 16, 256, 0, stream>>>((const float4*)tvec, Wo, orow);
    k4_bcast<<<(BB * SS) / 4, 256, 0, stream>>>((const float4*)orow, (float4*)out);
}

// Round 5
// 111.902 us; speedup vs baseline: 2.5118x; 1.0411x over previous
//
#include <hip/hip_runtime.h>

// Problem constants: B=4, S=2048, D=1024, G=256, I=1024, H=16
#define BB 4
#define SS 2048
#define DD 1024
#define II 1024

// Algebraic collapse (verified rounds 1-4): keys identical across seq ->
// softmax uniform -> out[b,s,:] = ((mean_s x[b,s,:]) @ Wv) @ Wo broadcast
// over s. Wq/Wk/structure_features unused.
//
// Round 5: widen the two latency-limited middle stages.
//   k1   (512 blk x 256):  x -> pbuf[4][128][1024]          (~5.5 us, BW)
//   kred ( 64 blk x 256):  pbuf -> xbar  (b x 16 col-groups) (~0.5 us)
//   kg   ( 64 blk x 1024): t = xbar@Wv ; orow = t@Wo         (~1.5 us each)
//   k4   (2048 blk x 256): broadcast orow -> out             (~5.5 us, BW)

constexpr int JP = 128;            // partials per batch
constexpr int ROWS1 = SS / JP;     // 16 rows per k1 block

// k1: pbuf[g][:] = sum of 16 consecutive rows of x  (g = b*128 + j)
__global__ __launch_bounds__(256)
void k1_partial(const float4* __restrict__ x, float4* __restrict__ pbuf) {
    const int g = blockIdx.x;                 // 512 blocks
    const float4* xr = x + (size_t)g * ROWS1 * (DD / 4) + threadIdx.x;
    float4 a = make_float4(0.f, 0.f, 0.f, 0.f);
    #pragma unroll
    for (int r = 0; r < ROWS1; ++r) {
        float4 v = xr[(size_t)r * (DD / 4)];
        a.x += v.x; a.y += v.y; a.z += v.z; a.w += v.w;
    }
    pbuf[(size_t)g * (DD / 4) + threadIdx.x] = a;
}

// kred: xbar[b][dg*64 : +64] = (1/S) * sum_j pbuf[b][j][slice]
// 64 blocks = (b, dg); thread = (jg 0..15, c4 0..15); each sums 8 j's.
__global__ __launch_bounds__(256)
void kred(const float4* __restrict__ pbuf, float4* __restrict__ xbar) {
    const int b = blockIdx.x >> 4, dg = blockIdx.x & 15;
    const int c4 = threadIdx.x & 15;          // float4 column within slice
    const int jg = threadIdx.x >> 4;          // 16 j-groups of 8
    const float4* p = pbuf + ((size_t)b * JP + jg * 8) * (DD / 4) + dg * 16 + c4;
    float4 a = make_float4(0.f, 0.f, 0.f, 0.f);
    #pragma unroll
    for (int j = 0; j < 8; ++j) {
        float4 v = p[(size_t)j * (DD / 4)];
        a.x += v.x; a.y += v.y; a.z += v.z; a.w += v.w;
    }
    __shared__ float4 red[16][16];            // 4 KB
    red[jg][c4] = a;
    __syncthreads();
    if (threadIdx.x < 16) {
        float4 s = make_float4(0.f, 0.f, 0.f, 0.f);
        #pragma unroll
        for (int q = 0; q < 16; ++q) {
            float4 v = red[q][threadIdx.x];
            s.x += v.x; s.y += v.y; s.z += v.z; s.w += v.w;
        }
        const float sc = 1.0f / (float)SS;
        xbar[b * (DD / 4) + dg * 16 + threadIdx.x] =
            make_float4(s.x * sc, s.y * sc, s.z * sc, s.w * sc);
    }
}

// kg: out[b][i0:i0+16] = vec[b][:] @ W   (vec: [4][1024], W: [1024][1024])
// 64 blocks x 1024 threads; 64-way k-split (16 k each); wave = 4 ks x 16 cols
// -> four 64B segments per load instruction (fully coalesced sectors).
__global__ __launch_bounds__(1024)
void kg_gemv(const float4* __restrict__ vec, const float* __restrict__ W,
             float* __restrict__ out) {
    __shared__ float xs[BB * DD];             // 16 KB
    const int tid = threadIdx.x;
    ((float4*)xs)[tid] = vec[tid];            // 1024 float4 = all 4096 floats
    __syncthreads();

    const int i0 = blockIdx.x * 16;
    const int il = tid & 15, ks = tid >> 4;   // 64 k-groups of 16
    float a0 = 0.f, a1 = 0.f, a2 = 0.f, a3 = 0.f;
    #pragma unroll
    for (int kk = 0; kk < 16; ++kk) {
        const int k = ks * 16 + kk;
        const float w = W[(size_t)k * DD + i0 + il];
        a0 += xs[0 * DD + k] * w;
        a1 += xs[1 * DD + k] * w;
        a2 += xs[2 * DD + k] * w;
        a3 += xs[3 * DD + k] * w;
    }

    __shared__ float red[64 * 64];            // red[ks][b*16+il], 16 KB
    red[ks * 64 +  0 + il] = a0;
    red[ks * 64 + 16 + il] = a1;
    red[ks * 64 + 32 + il] = a2;
    red[ks * 64 + 48 + il] = a3;
    __syncthreads();
    if (tid < 64) {                           // addr = q*64 + tid: conflict-free
        float s = 0.f;
        #pragma unroll
        for (int q = 0; q < 64; ++q) s += red[q * 64 + tid];
        const int b = tid >> 4, i = tid & 15;
        out[b * DD + i0 + i] = s;
    }
}

// k4: out[b][s][:] = orow[b][:], 4 rows per block, float4 stores
__global__ __launch_bounds__(256)
void k4_bcast(const float4* __restrict__ orow, float4* __restrict__ out) {
    const int g = blockIdx.x;                 // 2048 blocks
    const int b = g >> 9;
    const int s0 = (g & 511) * 4;
    const float4 c = orow[b * (DD / 4) + threadIdx.x];
    float4* o = out + (size_t)(b * SS + s0) * (DD / 4) + threadIdx.x;
    #pragma unroll
    for (int r = 0; r < 4; ++r) o[(size_t)r * (DD / 4)] = c;
}

extern "C" void kernel_launch(void* const* d_in, const int* in_sizes, int n_in,
                              void* d_out, int out_size, void* d_ws, size_t ws_size,
                              hipStream_t stream) {
    const float* x  = (const float*)d_in[0];  // inputs_embeds [B,S,D]
    const float* Wv = (const float*)d_in[4];  // [D,I]
    const float* Wo = (const float*)d_in[5];  // [I,D]
    float* out = (float*)d_out;

    float* pbuf = (float*)d_ws;                       // BB*JP*DD floats (2 MB)
    float* xbar = pbuf + (size_t)BB * JP * DD;        // [4][1024]
    float* tvec = xbar + (size_t)BB * DD;             // [4][1024]
    float* orow = tvec + (size_t)BB * II;             // [4][1024]

    k1_partial<<<BB * JP, 256, 0, stream>>>((const float4*)x, (float4*)pbuf);
    kred<<<64, 256, 0, stream>>>((const float4*)pbuf, (float4*)xbar);
    kg_gemv<<<II / 16, 1024, 0, stream>>>((const float4*)xbar, Wv, tvec);
    kg_gemv<<<DD / 16, 1024, 0, stream>>>((const float4*)tvec, Wo, orow);
    k4_bcast<<<(BB * SS) / 4, 256, 0, stream>>>((const float4*)orow, (float4*)out);
}